// Round 7
// baseline (37.853 us; speedup 1.0000x reference)
//
#include <hip/hip_runtime.h>
#include <hip/hip_bf16.h>

// TrajectoryInformedSplatAttention — rolling-pipeline single kernel.
// B=4, S=4096, D=1024, maxd=8.
//
// traj[b,s,:] = sum_{jr=0..8} g[s][jr] * emb[b, s-8+jr, :]   (telescoped)
//   g[jr] = (c[jr-1]-c[jr])/wsum, c[j] = lin(s,j)*q[i], i=s-8+j
//   q = tanh(2*mag)/mag (0 if mag<=1e-6), wsum = max(sum lin*tanh(2*mag),1e-8)
//
// Structure: 256 blocks x 512 threads (float2/thread over D=1024). Each block
// owns 64 output rows, processed as 4 sub-chunks of 16 with a rolling 24-row
// register window. Prefetch of sub-chunk j+1 is issued BEFORE computing j and
// stays in flight across the three LDS-only barriers (raw s_barrier +
// lgkmcnt(0) — NOT __syncthreads, whose vmcnt(0) drain was the R6 stall).
// Only LDS (part/smagw/sq/gco) is cross-thread; win[] is thread-private, so
// lgkm-only barriers are sufficient for correctness.

constexpr int B_ = 4;
constexpr int S_ = 4096;
constexpr int D_ = 1024;
constexpr int MAXD = 8;
constexpr int SUB   = 16;             // rows per sub-chunk
constexpr int NSUB  = 4;              // sub-chunks per block
constexpr int SPAN  = SUB * NSUB;     // 64 output rows per block
constexpr int WIN   = SUB + MAXD;     // 24-row register window
constexpr int NDIF0 = WIN - 1;        // 23 diffs in first sub-chunk
constexpr int NCH   = S_ / SPAN;      // 64 span-chunks per batch
constexpr int NWG   = B_ * NCH;       // 256 blocks
constexpr int NXCD  = 8;

__device__ __forceinline__ void lds_barrier() {
    // Drain LDS ops only; leave global loads in flight across the barrier.
    asm volatile("s_waitcnt lgkmcnt(0)" ::: "memory");
    __builtin_amdgcn_s_barrier();
}

__global__ __launch_bounds__(512, 2)
void traj_splat_kernel(const float* __restrict__ emb, float* __restrict__ out) {
    // XCD swizzle (NWG % 8 == 0 -> bijective): consecutive lin on one XCD are
    // consecutive span-chunks -> 8-row inter-block halo is an L2 hit.
    const int bid = blockIdx.x;
    const int lin = (bid % NXCD) * (NWG / NXCD) + bid / NXCD;
    const int sc  = lin & (NCH - 1);
    const int b   = lin >> 6;             // lin / 64

    const int s0b  = sc * SPAN;
    const int lane = threadIdx.x & 63;
    const int wave = threadIdx.x >> 6;    // 8 waves
    const int d0   = threadIdx.x * 2;     // 512 threads * 2 floats = 1024 = D

    const float* __restrict__ embB = emb + (size_t)b * S_ * D_;
    float* __restrict__ outB = out + (size_t)b * S_ * D_;

    __shared__ float part[NDIF0][33];     // 32 partials/diff + pad
    __shared__ float smagw[SPAN + MAXD];  // block-local diffs 0..70
    __shared__ float sq[SPAN + MAXD];
    __shared__ float gco[SUB][12];        // per-sub-chunk coefficients

    float2 win[WIN];
    float2 nxt[SUB];

    // Initial window: rows s0b-8 .. s0b+15 (zeros below row 0)
    #pragma unroll
    for (int r = 0; r < WIN; ++r) {
        const int row = s0b - MAXD + r;
        win[r] = (row >= 0) ? *(const float2*)(embB + (size_t)row * D_ + d0)
                            : make_float2(0.f, 0.f);
    }

    #pragma unroll
    for (int j = 0; j < NSUB; ++j) {
        const int r0 = s0b + j * SUB;

        // ---- Prefetch next sub-chunk rows r0+16..r0+31 (always in-range) ----
        if (j + 1 < NSUB) {
            #pragma unroll
            for (int t = 0; t < SUB; ++t)
                nxt[t] = *(const float2*)(embB + (size_t)(r0 + SUB + t) * D_ + d0);
        }

        // ---- Diff partials: j=0 computes 23 diffs, later sub-chunks 16 new ----
        const int ndiff = (j == 0) ? NDIF0 : SUB;
        const int woff  = (j == 0) ? 0 : (MAXD - 1);   // win idx of first diff
        const int dbase = (j == 0) ? 0 : (16 * j + 7); // block-local diff base
        #pragma unroll
        for (int t = 0; t < NDIF0; ++t) {
            if (t < ndiff) {
                const float2 a = win[t + woff], c = win[t + woff + 1];
                const float dx = c.x - a.x, dy = c.y - a.y;
                float sum = dx * dx + dy * dy;
                sum += __shfl_xor(sum, 32, 64);
                sum += __shfl_xor(sum, 16, 64);
                sum += __shfl_xor(sum,  8, 64);
                sum += __shfl_xor(sum,  4, 64);
                if (lane < 4) part[t][wave * 4 + lane] = sum;
            }
        }
        lds_barrier();

        // ---- Finalize magnitudes (full-D) into rolling LDS scalar arrays ----
        if ((int)threadIdx.x < ndiff) {
            const int t = threadIdx.x;
            float s2 = 0.f;
            #pragma unroll
            for (int k = 0; k < 32; ++k) s2 += part[t][k];
            const float mag = sqrtf(s2);
            const float mw  = tanhf(2.f * mag);
            smagw[dbase + t] = mw;
            sq[dbase + t]    = (mag > 1e-6f) ? (mw / mag) : 0.f;
        }
        lds_barrier();

        // ---- Telescoped coefficients for s = r0..r0+15 ----
        if (threadIdx.x < SUB) {
            const int sl = threadIdx.x;
            const int s  = r0 + sl;
            const int ws = min(MAXD, s);
            const int lo = MAXD - ws;
            const float rden = 0.9f / (float)max(ws - 1, 1);

            float cpad[MAXD + 2];
            #pragma unroll
            for (int t = 0; t < MAXD + 2; ++t) cpad[t] = 0.f;

            float wsum = 0.f;
            #pragma unroll
            for (int jj = 0; jj < MAXD; ++jj) {
                if (jj >= lo) {
                    const int di = 16 * j + sl + jj;     // block-local diff idx
                    const float lin2 = (ws > 1) ? (0.1f + rden * (float)(jj - lo)) : 0.1f;
                    wsum += lin2 * smagw[di];
                    cpad[jj + 1] = lin2 * sq[di];
                }
            }
            const float inv = 1.f / fmaxf(wsum, 1e-8f);
            #pragma unroll
            for (int jr = 0; jr <= MAXD; ++jr)
                gco[sl][jr] = (cpad[jr] - cpad[jr + 1]) * inv;
        }
        lds_barrier();

        // ---- Outputs: 16 rows x 9-FMA stencil from registers ----
        float* op = outB + (size_t)r0 * D_ + d0;
        #pragma unroll
        for (int sl = 0; sl < SUB; ++sl) {
            const float4 g0 = *(const float4*)&gco[sl][0];
            const float4 g1 = *(const float4*)&gco[sl][4];
            const float  g8 = gco[sl][8];

            float2 acc;
            acc.x = g0.x * win[sl].x;
            acc.y = g0.x * win[sl].y;
            const float gs[8] = {g0.y, g0.z, g0.w, g1.x, g1.y, g1.z, g1.w, g8};
            #pragma unroll
            for (int jr = 1; jr <= MAXD; ++jr) {
                acc.x += gs[jr - 1] * win[sl + jr].x;
                acc.y += gs[jr - 1] * win[sl + jr].y;
            }
            *(float2*)(op + (size_t)sl * D_) = acc;
        }

        // ---- Roll window: keep 8-row tail, bring in prefetched rows ----
        if (j + 1 < NSUB) {
            #pragma unroll
            for (int t = 0; t < MAXD; ++t) win[t] = win[t + SUB];
            #pragma unroll
            for (int t = 0; t < SUB; ++t) win[MAXD + t] = nxt[t];
        }
    }
}

extern "C" void kernel_launch(void* const* d_in, const int* in_sizes, int n_in,
                              void* d_out, int out_size, void* d_ws, size_t ws_size,
                              hipStream_t stream) {
    const float* emb = (const float*)d_in[0];
    float* out = (float*)d_out;

    dim3 grid(NWG);      // 256 blocks, swizzled in-kernel
    dim3 block(512);
    traj_splat_kernel<<<grid, block, 0, stream>>>(emb, out);
}

// Round 9
// 26.318 us; speedup vs baseline: 1.4383x; 1.4383x over previous
//
#include <hip/hip_runtime.h>
#include <hip/hip_bf16.h>

// TrajectoryInformedSplatAttention — R6 skeleton + DPP wave reduction.
// B=4, S=4096, D=1024, maxd=8.
//
// traj[b,s,:] = sum_{jr=0..8} g[s][jr] * emb[b, s-8+jr, :]   (telescoped)
//   g[jr] = (c[jr-1]-c[jr])/wsum, c[j] = lin(s,j)*q[i], i=s-8+j
//   q = tanh(2*mag)/mag (0 if mag<=1e-6), wsum = max(sum lin*tanh(2*mag),1e-8)
//
// vs R6: the 4-level __shfl_xor butterfly (156 LDS-pipe ops/wave) is replaced
// by the canonical GCN DPP reduce (row_shr 1/2/4/8 + row_bcast15/31 — pure
// VALU, no LDS pipe). Lane 63 holds the wave total; finalize reads 8 partials.
// R8 fix: DPP ctrl/row_mask must be compile-time constants -> template params.

constexpr int B_ = 4;
constexpr int S_ = 4096;
constexpr int D_ = 1024;
constexpr int MAXD  = 8;
constexpr int CHUNK = 32;
constexpr int ROWS  = CHUNK + MAXD;      // 40-row register window
constexpr int NDIFF = ROWS - 1;          // 39 adjacent diffs
constexpr int NCH   = S_ / CHUNK;        // 128 s-chunks
constexpr int NWG   = B_ * NCH;          // 512 blocks
constexpr int NXCD  = 8;

// x += dpp_shifted(x); old=0 so shifted-in / unmasked rows contribute 0.
template <int CTRL, int ROW_MASK>
__device__ __forceinline__ float dpp_add(float x) {
    const int t = __builtin_amdgcn_update_dpp(0, __float_as_int(x),
                                              CTRL, ROW_MASK, 0xf, false);
    return x + __int_as_float(t);
}

// Full 64-lane sum -> lane 63. row_shr:N = 0x110|N, bcast15=0x142, bcast31=0x143.
__device__ __forceinline__ float wave_reduce_dpp(float x) {
    x = dpp_add<0x111, 0xf>(x);   // += lane-1
    x = dpp_add<0x112, 0xf>(x);   // += lane-2
    x = dpp_add<0x114, 0xf>(x);   // += lane-4
    x = dpp_add<0x118, 0xf>(x);   // += lane-8   -> lane 15+16k = row sums
    x = dpp_add<0x142, 0xa>(x);   // rows 1,3 += bcast(lane15/47)
    x = dpp_add<0x143, 0xc>(x);   // rows 2,3 += bcast(lane31)   -> lane63 total
    return x;
}

__global__ __launch_bounds__(512, 4)
void traj_splat_kernel(const float* __restrict__ emb, float* __restrict__ out) {
    // XCD swizzle (NWG % 8 == 0 -> bijective): consecutive lin on one XCD are
    // consecutive s-chunks -> 8-row halo is an L2 hit.
    const int bid = blockIdx.x;
    const int lin = (bid % NXCD) * (NWG / NXCD) + bid / NXCD;
    const int schunk = lin & (NCH - 1);
    const int b      = lin >> 7;

    const int s0   = schunk * CHUNK;
    const int lane = threadIdx.x & 63;
    const int wave = threadIdx.x >> 6;    // 8 waves
    const int d0   = threadIdx.x * 2;     // 512 threads * 2 floats = 1024 = D

    const float* __restrict__ embB = emb + (size_t)b * S_ * D_;

    __shared__ float part[NDIFF][9];      // 8 wave-sums/diff + 1 pad
    __shared__ float smagw[NDIFF];
    __shared__ float sq[NDIFF];
    __shared__ float gco[CHUNK][12];

    // ---- Phase A: 40-row window, float2/thread (independent loads, ILP) ----
    float2 win[ROWS];
    #pragma unroll
    for (int r = 0; r < ROWS; ++r) {
        const int row = s0 - MAXD + r;    // max = s0+31 <= S-1
        win[r] = (row >= 0) ? *(const float2*)(embB + (size_t)row * D_ + d0)
                            : make_float2(0.f, 0.f);
    }

    // ---- Phase B: 39 full-D diff magnitudes via DPP (VALU-only reduce) ----
    #pragma unroll
    for (int li = 0; li < NDIFF; ++li) {
        const float2 a = win[li], c = win[li + 1];
        const float dx = c.x - a.x, dy = c.y - a.y;
        float sum = dx * dx + dy * dy;
        sum = wave_reduce_dpp(sum);
        if (lane == 63) part[li][wave] = sum;
    }
    __syncthreads();

    if (threadIdx.x < NDIFF) {
        const int li = threadIdx.x;
        float s2 = 0.f;
        #pragma unroll
        for (int k = 0; k < 8; ++k) s2 += part[li][k];
        const float mag = sqrtf(s2);                     // FULL-D magnitude
        const float mw  = tanhf(2.f * mag);
        smagw[li] = mw;
        sq[li]    = (mag > 1e-6f) ? (mw / mag) : 0.f;
    }
    __syncthreads();

    // ---- Phase C1: CHUNK threads build the 9 telescoped coefficients per s ----
    if (threadIdx.x < CHUNK) {
        const int sl = threadIdx.x;
        const int s  = s0 + sl;
        const int ws = min(MAXD, s);
        const int lo = MAXD - ws;
        const float rden = 0.9f / (float)max(ws - 1, 1);

        float cpad[MAXD + 2];
        #pragma unroll
        for (int t = 0; t < MAXD + 2; ++t) cpad[t] = 0.f;

        float wsum = 0.f;
        #pragma unroll
        for (int j = 0; j < MAXD; ++j) {
            if (j >= lo) {
                const int li = sl + j;               // diff at global index s-8+j
                const float lin2 = (ws > 1) ? (0.1f + rden * (float)(j - lo)) : 0.1f;
                wsum += lin2 * smagw[li];
                cpad[j + 1] = lin2 * sq[li];
            }
        }
        const float inv = 1.f / fmaxf(wsum, 1e-8f);
        #pragma unroll
        for (int jr = 0; jr <= MAXD; ++jr)
            gco[sl][jr] = (cpad[jr] - cpad[jr + 1]) * inv;
    }
    __syncthreads();

    // ---- Phase C2: outputs from registers, broadcast coefficient reads ----
    float* outB = out + ((size_t)b * S_ + s0) * D_ + d0;
    #pragma unroll
    for (int sl = 0; sl < CHUNK; ++sl) {
        const float4 g0 = *(const float4*)&gco[sl][0];   // g[0..3] (broadcast)
        const float4 g1 = *(const float4*)&gco[sl][4];   // g[4..7]
        const float  g8 = gco[sl][8];

        float2 acc;
        acc.x = g0.x * win[sl].x;
        acc.y = g0.x * win[sl].y;
        const float gs[8] = {g0.y, g0.z, g0.w, g1.x, g1.y, g1.z, g1.w, g8};
        #pragma unroll
        for (int jr = 1; jr <= MAXD; ++jr) {
            const float g = gs[jr - 1];
            acc.x += g * win[sl + jr].x;
            acc.y += g * win[sl + jr].y;
        }
        *(float2*)(outB + (size_t)sl * D_) = acc;
    }
}

extern "C" void kernel_launch(void* const* d_in, const int* in_sizes, int n_in,
                              void* d_out, int out_size, void* d_ws, size_t ws_size,
                              hipStream_t stream) {
    const float* emb = (const float*)d_in[0];
    float* out = (float*)d_out;

    dim3 grid(NWG);      // 512 blocks, swizzled in-kernel
    dim3 block(512);
    traj_splat_kernel<<<grid, block, 0, stream>>>(emb, out);
}